// Round 1
// baseline (764.217 us; speedup 1.0000x reference)
//
#include <hip/hip_runtime.h>
#include <math.h>

// ---------------- degree / norm ----------------
__global__ void k_set_deg(float* dv, int N) {
    int i = blockIdx.x * blockDim.x + threadIdx.x;
    if (i < N) dv[i] = 1.0f;               // self-loop weight
}

__global__ void k_deg_accum(const int* __restrict__ col, const float* __restrict__ w,
                            float* dv, int E) {
    int e = blockIdx.x * blockDim.x + threadIdx.x;
    if (e < E) atomicAdd(&dv[col[e]], w[e]);
}

__global__ void k_dinv(float* dv, int N) {
    int i = blockIdx.x * blockDim.x + threadIdx.x;
    if (i < N) dv[i] = rsqrtf(dv[i]);      // deg >= 1 always
}

__global__ void k_norm(const int* __restrict__ row, const int* __restrict__ col,
                       const float* __restrict__ w, const float* __restrict__ dv,
                       float* __restrict__ nrm, int E) {
    int e = blockIdx.x * blockDim.x + threadIdx.x;
    if (e < E) nrm[e] = dv[row[e]] * w[e] * dv[col[e]];
}

// ---------------- x @ W1  (N x 256 @ 256 x 16) ----------------
__global__ __launch_bounds__(256) void k_xw1(const float* __restrict__ x,
                                             const float* __restrict__ W1,
                                             float* __restrict__ h, int N) {
    __shared__ float xs[16][257];          // +1 pad: banks (r+k)%32 distinct
    __shared__ float wsh[256 * 16];
    int t = threadIdx.x;
    int base = blockIdx.x * 16;

    const float4* w4 = (const float4*)W1;
    float4* wsh4 = (float4*)wsh;
#pragma unroll
    for (int i = 0; i < 4; i++) wsh4[t + i * 256] = w4[t + i * 256];

    const float4* x4 = (const float4*)x;
    long xbase4 = (long)base * 64;
#pragma unroll
    for (int i = 0; i < 4; i++) {
        int p4 = t + i * 256;              // 0..1023 float4s = 16 rows x 64
        int r = p4 >> 6;
        int k = (p4 & 63) * 4;
        if (base + r < N) {
            float4 v = x4[xbase4 + p4];
            xs[r][k] = v.x; xs[r][k + 1] = v.y; xs[r][k + 2] = v.z; xs[r][k + 3] = v.w;
        }
    }
    __syncthreads();

    int r = t >> 4, j = t & 15;
    if (base + r < N) {
        float acc = 0.f;
#pragma unroll
        for (int k = 0; k < 256; k++) acc += xs[r][k] * wsh[k * 16 + j];
        h[(long)(base + r) * 16 + j] = acc;
    }
}

// ---------------- self-loop init: agg = dinv^2 * h ----------------
__global__ void k_agg_init(const float* __restrict__ h, const float* __restrict__ dv,
                           float* __restrict__ agg, int N16) {
    int i = blockIdx.x * blockDim.x + threadIdx.x;
    if (i < N16) {
        float d = dv[i >> 4];
        agg[i] = d * d * h[i];
    }
}

// ---------------- edge scatter: agg[col] += norm * h[row], 16 feats ----------------
__global__ void k_scatter(const int* __restrict__ row, const int* __restrict__ col,
                          const float* __restrict__ nrm, const float* __restrict__ h,
                          float* agg, int E) {
    int idx = blockIdx.x * blockDim.x + threadIdx.x;
    int e = idx >> 4, j = idx & 15;
    if (e < E) {
        int r = row[e], c = col[e];
        float v = nrm[e] * h[r * 16 + j];
        atomicAdd(&agg[c * 16 + j], v);
    }
}

// ---------------- h1 = relu(agg1 + b1) ----------------
__global__ void k_relu_bias(const float* __restrict__ agg, const float* __restrict__ b1,
                            float* __restrict__ h, int N16) {
    int i = blockIdx.x * blockDim.x + threadIdx.x;
    if (i < N16) h[i] = fmaxf(agg[i] + b1[i & 15], 0.f);
}

// ---------------- out = log_softmax(agg2 @ W2 + b2), wave per row ----------------
__global__ __launch_bounds__(256) void k_out(const float* __restrict__ agg2,
                                             const float* __restrict__ W2,
                                             const float* __restrict__ b2,
                                             float* __restrict__ out, int N) {
    int lane = threadIdx.x & 63;
    int wave = threadIdx.x >> 6;
    int rowi = blockIdx.x * 4 + wave;
    if (rowi >= N) return;

    float a[16];
#pragma unroll
    for (int j = 0; j < 16; j++) a[j] = agg2[(long)rowi * 16 + j];

    float acc = -INFINITY;
    if (lane < 40) {
        acc = b2[lane];
#pragma unroll
        for (int j = 0; j < 16; j++) acc += a[j] * W2[j * 40 + lane];
    }
    float m = acc;
#pragma unroll
    for (int off = 32; off; off >>= 1) m = fmaxf(m, __shfl_xor(m, off));
    float ex = (lane < 40) ? expf(acc - m) : 0.f;
    float s = ex;
#pragma unroll
    for (int off = 32; off; off >>= 1) s += __shfl_xor(s, off);
    if (lane < 40) out[(long)rowi * 40 + lane] = acc - m - logf(s);
}

extern "C" void kernel_launch(void* const* d_in, const int* in_sizes, int n_in,
                              void* d_out, int out_size, void* d_ws, size_t ws_size,
                              hipStream_t stream) {
    const float* x  = (const float*)d_in[0];
    const int*   ei = (const int*)d_in[1];
    const float* ew = (const float*)d_in[2];
    const float* W1 = (const float*)d_in[3];
    const float* b1 = (const float*)d_in[4];
    const float* W2 = (const float*)d_in[5];
    const float* b2 = (const float*)d_in[6];
    float* out = (float*)d_out;

    int N = in_sizes[0] / 256;
    int E = in_sizes[2];
    const int* row = ei;
    const int* col = ei + E;

    float* ws = (float*)d_ws;
    float* dv   = ws;                      // N
    float* nrm  = dv + N;                  // E
    float* h1   = nrm + E;                 // N*16 (xW1, later relu'd h1)
    float* agg1 = h1 + (size_t)N * 16;     // N*16
    float* agg2 = agg1 + (size_t)N * 16;   // N*16

    const int B = 256;
    long e16 = (long)E * 16;

    k_set_deg  <<<(N + B - 1) / B, B, 0, stream>>>(dv, N);
    k_deg_accum<<<(E + B - 1) / B, B, 0, stream>>>(col, ew, dv, E);
    k_dinv     <<<(N + B - 1) / B, B, 0, stream>>>(dv, N);
    k_norm     <<<(E + B - 1) / B, B, 0, stream>>>(row, col, ew, dv, nrm, E);

    k_xw1      <<<(N + 15) / 16, 256, 0, stream>>>(x, W1, h1, N);

    k_agg_init <<<(N * 16 + B - 1) / B, B, 0, stream>>>(h1, dv, agg1, N * 16);
    k_scatter  <<<(int)((e16 + B - 1) / B), B, 0, stream>>>(row, col, nrm, h1, agg1, E);
    k_relu_bias<<<(N * 16 + B - 1) / B, B, 0, stream>>>(agg1, b1, h1, N * 16);

    k_agg_init <<<(N * 16 + B - 1) / B, B, 0, stream>>>(h1, dv, agg2, N * 16);
    k_scatter  <<<(int)((e16 + B - 1) / B), B, 0, stream>>>(row, col, nrm, h1, agg2, E);

    k_out      <<<(N + 3) / 4, 256, 0, stream>>>(agg2, W2, b2, out, N);
}